// Round 1
// baseline (183.883 us; speedup 1.0000x reference)
//
#include <hip/hip_runtime.h>
#include <math.h>

// Problem constants (fixed by reference setup_inputs)
#define HH 512
#define WW 1024
#define HW (HH*WW)
#define TOPK 200
#define NMSPAD 3            // (7-1)/2
#define THRESH 0.1f
#define CAP 65536           // max candidate local maxima (>= HW/16 bound for 7x7 NMS)
#define NBINS 16384
#define SUBCAP 4096

// ---------------- helpers ----------------
__device__ __forceinline__ int score_bin(float s) {
    // monotone non-decreasing binning of scores in (0.1, 1]
    int b = (int)((s - THRESH) * (float)(NBINS / 0.9f));
    if (b < 0) b = 0;
    if (b > NBINS - 1) b = NBINS - 1;
    return b;
}

// ---------------- K0: init counters + histogram ----------------
__global__ void k0_init(int* __restrict__ nc, int* __restrict__ hist) {
    int i = blockIdx.x * blockDim.x + threadIdx.x;
    if (i == 0) *nc = 0;
    if (i < NBINS) hist[i] = 0;
}

// ---------------- K1: threshold + 7x7 NMS, compact candidates ----------------
// block (32,8); tile (32+6)x(8+6) staged in LDS; separable row-max then col-max.
__global__ __launch_bounds__(256) void k1_nms(const float* __restrict__ hmp,
                                              int* __restrict__ nc,
                                              float* __restrict__ cscore,
                                              int* __restrict__ cidx) {
    const int BX = 32, BY = 8, TW = BX + 6, TH = BY + 6;
    __shared__ float A[TH][TW + 2];   // +2 pad: stride 40 breaks pow2 bank stride
    __shared__ float R[TH][BX];
    int lx = threadIdx.x, ly = threadIdx.y;
    int x0 = blockIdx.x * BX, y0 = blockIdx.y * BY;
    int tid = ly * BX + lx;

    for (int t = tid; t < TH * TW; t += 256) {
        int r = t / TW, c = t % TW;
        int gy = y0 - NMSPAD + r, gx = x0 - NMSPAD + c;
        float v = -INFINITY;  // reduce_window pads with init = -inf
        if (gy >= 0 && gy < HH && gx >= 0 && gx < WW) {
            float h = hmp[gy * WW + gx];
            v = (h > THRESH) ? h : -1.0f;
        }
        A[r][c] = v;
    }
    __syncthreads();
    for (int t = tid; t < TH * BX; t += 256) {
        int r = t / BX, c = t % BX;
        float m = A[r][c];
        #pragma unroll
        for (int d = 1; d < 7; ++d) m = fmaxf(m, A[r][c + d]);
        R[r][c] = m;
    }
    __syncthreads();
    float v = A[ly + NMSPAD][lx + NMSPAD];
    if (v > 0.0f) {                       // candidate must be > THRESH (thresholded)
        float m = R[ly][lx];
        #pragma unroll
        for (int d = 1; d < 7; ++d) m = fmaxf(m, R[ly + d][lx]);
        if (v == m) {                     // local max of its 7x7 window (ties kept, like ref)
            int pos = atomicAdd(nc, 1);
            if (pos < CAP) {
                cscore[pos] = v;
                cidx[pos] = (y0 + ly) * WW + (x0 + lx);
            }
        }
    }
}

// ---------------- K2: score histogram ----------------
__global__ void k2_hist(const int* __restrict__ nc,
                        const float* __restrict__ cscore,
                        int* __restrict__ hist) {
    int n = min(*nc, CAP);
    for (int i = blockIdx.x * blockDim.x + threadIdx.x; i < n;
         i += gridDim.x * blockDim.x) {
        atomicAdd(&hist[score_bin(cscore[i])], 1);
    }
}

// ---------------- K3: exact top-K selection + ordering (single block) --------
// cutoff bin cb == bin of K-th largest score (proof: suffix(b) monotone; see notes).
// Subset {bin >= cb} has size ~K + O(1); exact rank with top_k tie rule
// (higher score first, ties -> lower index). Output rows = valid centers sorted
// by flat idx (matches ref argsort(order_key)); V<K tail = lowest non-candidate
// indices (matches top_k over the -1 field).
__global__ __launch_bounds__(1024) void k3_select(const int* __restrict__ nc,
                                                  const int* __restrict__ hist,
                                                  const float* __restrict__ cscore,
                                                  const int* __restrict__ cidx,
                                                  int* __restrict__ out_center,
                                                  int* __restrict__ out_valid,
                                                  float* __restrict__ cy,
                                                  float* __restrict__ cx) {
    __shared__ int chunk[1024];
    __shared__ float ss[SUBCAP];
    __shared__ int sidx[SUBCAP];
    __shared__ int srank[SUBCAP];
    __shared__ int sselidx[TOPK];
    __shared__ int s_cb, s_m;
    int tid = threadIdx.x;
    int V = min(*nc, CAP);

    // per-thread 16-bin chunk sums
    int base = tid * 16, sum = 0;
    #pragma unroll
    for (int i = 0; i < 16; ++i) sum += hist[base + i];
    chunk[tid] = sum;
    if (tid == 0) s_m = 0;
    __syncthreads();

    if (tid == 0) {
        int acc = 0, cb = 0;
        for (int c = 1023; c >= 0; --c) {
            if (acc + chunk[c] >= TOPK) {
                for (int b = c * 16 + 15; b >= c * 16; --b) {
                    acc += hist[b];
                    if (acc >= TOPK) { cb = b; break; }
                }
                break;
            }
            acc += chunk[c];
        }
        s_cb = cb;   // 0 if total < K -> keep everything
    }
    __syncthreads();
    int cb = s_cb;

    // gather suffix subset into LDS
    for (int i = tid; i < V; i += 1024) {
        float s = cscore[i];
        if (score_bin(s) >= cb) {
            int p = atomicAdd(&s_m, 1);
            if (p < SUBCAP) { ss[p] = s; sidx[p] = cidx[i]; }
        }
    }
    __syncthreads();
    int m = min(s_m, SUBCAP);

    // exact rank (top_k order) within subset
    for (int i = tid; i < m; i += 1024) {
        float si = ss[i]; int ii = sidx[i]; int r = 0;
        for (int j = 0; j < m; ++j) {
            float sj = ss[j];
            r += (sj > si) || (sj == si && sidx[j] < ii);
        }
        srank[i] = r;
    }
    __syncthreads();

    // selected (rank < K): output position = order by flat idx among selected
    for (int i = tid; i < m; i += 1024) {
        if (srank[i] < TOPK) {
            int ii = sidx[i];
            int pos = 0;
            for (int j = 0; j < m; ++j)
                pos += (srank[j] < TOPK) && (sidx[j] < ii);
            int y = ii >> 10, x = ii & (WW - 1);
            out_center[2 * pos] = y;
            out_center[2 * pos + 1] = x;
            out_valid[pos] = 1;
            cy[pos] = (float)y;
            cx[pos] = (float)x;
            sselidx[pos] = ii;
        }
    }
    __syncthreads();

    // V < K tail: lowest non-candidate flat indices, invalid
    if (tid == 0 && V < TOPK) {
        int slot = V, t = 0, p = 0;
        while (slot < TOPK) {
            if (p < V && t == sselidx[p]) { t++; p++; }
            else {
                out_center[2 * slot] = t >> 10;
                out_center[2 * slot + 1] = t & (WW - 1);
                out_valid[slot] = 0;
                cy[slot] = 1e10f;
                cx[slot] = 1e10f;
                t++; slot++;
            }
        }
    }
}

// ---------------- K4: nearest-center assignment + thing mask ----------------
// Exact numpy-op-for-op f32 arithmetic (__f*_rn blocks fma contraction) so
// argmin ties resolve identically to the reference.
__global__ __launch_bounds__(256) void k4_assign(const int* __restrict__ sem,
                                                 const float* __restrict__ off,
                                                 const float* __restrict__ cy,
                                                 const float* __restrict__ cx,
                                                 int* __restrict__ out_inst) {
    int p = blockIdx.x * 256 + threadIdx.x;
    int y = p >> 10, x = p & (WW - 1);
    float ly = __fadd_rn((float)y, off[p]);        // offsets[0,0]
    float lx = __fadd_rn((float)x, off[HW + p]);   // offsets[0,1]
    float best = INFINITY;
    int bid = 0;
    for (int k = 0; k < TOPK; ++k) {
        float dy = __fsub_rn(cy[k], ly);           // wave-uniform -> s_load
        float dx = __fsub_rn(cx[k], lx);
        float d2 = __fadd_rn(__fmul_rn(dy, dy), __fmul_rn(dx, dx));
        if (d2 < best) { best = d2; bid = k; }     // strict < = first-occurrence argmin
    }
    int s = sem[p];
    unsigned t = (unsigned)(s - 11);               // THING_LIST = 11..18
    out_inst[p] = (t <= 7u) ? (bid + 1) : 0;
}

// ---------------- launch ----------------
extern "C" void kernel_launch(void* const* d_in, const int* in_sizes, int n_in,
                              void* d_out, int out_size, void* d_ws, size_t ws_size,
                              hipStream_t stream) {
    const int* sem = (const int*)d_in[0];
    const float* hmp = (const float*)d_in[1];
    const float* off = (const float*)d_in[2];
    int* out = (int*)d_out;

    // workspace layout (~579 KB)
    char* ws = (char*)d_ws;
    int* nc = (int*)ws;                                   // [0,4)
    int* hist = (int*)(ws + 64);                          // 64 KB
    float* cscore = (float*)(ws + 65600);                 // 256 KB
    int* cidx = (int*)(ws + 65600 + CAP * 4);             // 256 KB
    float* cy = (float*)(ws + 65600 + CAP * 8);           // 1 KB
    float* cx = (float*)(ws + 65600 + CAP * 8 + 1024);    // 1 KB

    int* out_inst = out;              // [1,H,W] int32
    int* out_center = out + HW;       // [1,K,2] int32 (y,x)
    int* out_valid = out + HW + 2 * TOPK;  // [K] 0/1

    k0_init<<<NBINS / 256, 256, 0, stream>>>(nc, hist);
    k1_nms<<<dim3(WW / 32, HH / 8), dim3(32, 8), 0, stream>>>(hmp, nc, cscore, cidx);
    k2_hist<<<64, 256, 0, stream>>>(nc, cscore, hist);
    k3_select<<<1, 1024, 0, stream>>>(nc, hist, cscore, cidx,
                                      out_center, out_valid, cy, cx);
    k4_assign<<<HW / 256, 256, 0, stream>>>(sem, off, cy, cx, out_inst);
}

// Round 2
// 122.074 us; speedup vs baseline: 1.5063x; 1.5063x over previous
//
#include <hip/hip_runtime.h>
#include <math.h>

// Problem constants (fixed by reference setup_inputs)
#define HH 512
#define WW 1024
#define HW (HH*WW)
#define TOPK 200
#define NMSPAD 3            // (7-1)/2
#define THRESH 0.1f
#define NBINS 16384
#define SUBCAP 4096
#define SLOTS 24            // per-block candidate slots; 7x7-NMS max for a 32x8
                            // block with distinct values is 16 -> 24 has margin
#define NBX 32              // grid x of k1 (WW/32)
#define NBY 64              // grid y of k1 (HH/8)
#define NB (NBX*NBY)        // 2048 blocks

// ---------------- helpers ----------------
__device__ __forceinline__ int score_bin(float s) {
    // monotone non-decreasing binning of scores in (0.1, 1]
    int b = (int)((s - THRESH) * (float)(NBINS / 0.9f));
    if (b < 0) b = 0;
    if (b > NBINS - 1) b = NBINS - 1;
    return b;
}

// ---------------- K1: threshold + 7x7 NMS -> per-block lists + histogram ----
// Per-block LDS compaction; NO same-address global atomics (R1 post-mortem:
// a single global counter serialized ~8192 wave-atomics -> 76 us).
__global__ __launch_bounds__(256) void k1_nms(const float* __restrict__ hmp,
                                              int* __restrict__ blkcnt,
                                              float* __restrict__ blkscore,
                                              int* __restrict__ blkidx,
                                              int* __restrict__ hist) {
    const int BX = 32, BY = 8, TW = BX + 6, TH = BY + 6;
    __shared__ float A[TH][TW + 2];   // stride 40 breaks pow2 bank stride
    __shared__ float R[TH][BX];
    __shared__ float lsc[SLOTS];
    __shared__ int   lid[SLOTS];
    __shared__ int   s_cnt;
    int lx = threadIdx.x, ly = threadIdx.y;
    int x0 = blockIdx.x * BX, y0 = blockIdx.y * BY;
    int tid = ly * BX + lx;
    if (tid == 0) s_cnt = 0;

    for (int t = tid; t < TH * TW; t += 256) {
        int r = t / TW, c = t % TW;
        int gy = y0 - NMSPAD + r, gx = x0 - NMSPAD + c;
        float v = -INFINITY;  // reduce_window pads with init = -inf
        if (gy >= 0 && gy < HH && gx >= 0 && gx < WW) {
            float h = hmp[gy * WW + gx];
            v = (h > THRESH) ? h : -1.0f;
        }
        A[r][c] = v;
    }
    __syncthreads();
    for (int t = tid; t < TH * BX; t += 256) {
        int r = t / BX, c = t % BX;
        float m = A[r][c];
        #pragma unroll
        for (int d = 1; d < 7; ++d) m = fmaxf(m, A[r][c + d]);
        R[r][c] = m;
    }
    __syncthreads();
    float v = A[ly + NMSPAD][lx + NMSPAD];
    if (v > 0.0f) {                       // thresholded candidate
        float m = R[ly][lx];
        #pragma unroll
        for (int d = 1; d < 7; ++d) m = fmaxf(m, R[ly + d][lx]);
        if (v == m) {                     // local max (ties kept, like ref)
            int p = atomicAdd(&s_cnt, 1); // LDS atomic: ~1.3/block, cheap
            if (p < SLOTS) { lsc[p] = v; lid[p] = (y0 + ly) * WW + (x0 + lx); }
        }
    }
    __syncthreads();
    int b = blockIdx.y * NBX + blockIdx.x;
    int cnt = min(s_cnt, SLOTS);
    if (tid == 0) blkcnt[b] = cnt;
    if (tid < cnt) {
        float s = lsc[tid];
        blkscore[b * SLOTS + tid] = s;
        blkidx[b * SLOTS + tid] = lid[tid];
        atomicAdd(&hist[score_bin(s)], 1);  // scattered over 16384 bins
    }
}

// ---------------- K3: exact top-K selection + ordering (single block) --------
// cutoff bin cb == bin of K-th largest score. Subset {bin >= cb} has size
// ~K + O(collisions); exact rank with top_k tie rule (higher score first,
// ties -> lower index). Output rows = valid centers sorted by flat idx
// (matches ref argsort(order_key)); V<K tail = lowest non-candidate indices.
__global__ __launch_bounds__(1024) void k3_select(const int* __restrict__ blkcnt,
                                                  const float* __restrict__ blkscore,
                                                  const int* __restrict__ blkidx,
                                                  const int* __restrict__ hist,
                                                  int* __restrict__ out_center,
                                                  int* __restrict__ out_valid,
                                                  float2* __restrict__ ctr2) {
    __shared__ int chunk[1024];
    __shared__ float ss[SUBCAP];
    __shared__ int sidx[SUBCAP];
    __shared__ int srank[SUBCAP];
    __shared__ int sselidx[TOPK];
    __shared__ int s_cb, s_m, s_V;
    int tid = threadIdx.x;

    // per-thread 16-bin chunk sums + total candidate count
    int base = tid * 16, sum = 0;
    #pragma unroll
    for (int i = 0; i < 16; ++i) sum += hist[base + i];
    chunk[tid] = sum;
    if (tid == 0) { s_m = 0; s_V = 0; }
    __syncthreads();
    int myv = 0;
    for (int b = tid; b < NB; b += 1024) myv += blkcnt[b];
    if (myv) atomicAdd(&s_V, myv);

    if (tid == 0) {
        int acc = 0, cb = 0;
        for (int c = 1023; c >= 0; --c) {
            if (acc + chunk[c] >= TOPK) {
                for (int b = c * 16 + 15; b >= c * 16; --b) {
                    acc += hist[b];
                    if (acc >= TOPK) { cb = b; break; }
                }
                break;
            }
            acc += chunk[c];
        }
        s_cb = cb;   // stays 0 if total < K -> keep everything
    }
    __syncthreads();
    int cb = s_cb;
    int V = s_V;

    // gather suffix subset from per-block lists into LDS
    for (int b = tid; b < NB; b += 1024) {
        int cnt = blkcnt[b];
        for (int s = 0; s < cnt; ++s) {
            float sc = blkscore[b * SLOTS + s];
            if (score_bin(sc) >= cb) {
                int p = atomicAdd(&s_m, 1);
                if (p < SUBCAP) { ss[p] = sc; sidx[p] = blkidx[b * SLOTS + s]; }
            }
        }
    }
    __syncthreads();
    int m = min(s_m, SUBCAP);

    // exact rank (top_k order) within subset
    for (int i = tid; i < m; i += 1024) {
        float si = ss[i]; int ii = sidx[i]; int r = 0;
        for (int j = 0; j < m; ++j) {
            float sj = ss[j];
            r += (sj > si) || (sj == si && sidx[j] < ii);
        }
        srank[i] = r;
    }
    __syncthreads();

    // selected (rank < K): output position = order by flat idx among selected
    for (int i = tid; i < m; i += 1024) {
        if (srank[i] < TOPK) {
            int ii = sidx[i];
            int pos = 0;
            for (int j = 0; j < m; ++j)
                pos += (srank[j] < TOPK) && (sidx[j] < ii);
            int y = ii >> 10, x = ii & (WW - 1);
            out_center[2 * pos] = y;
            out_center[2 * pos + 1] = x;
            out_valid[pos] = 1;
            ctr2[pos] = make_float2((float)y, (float)x);
            sselidx[pos] = ii;
        }
    }
    __syncthreads();

    // V < K tail: lowest non-candidate flat indices, invalid
    if (tid == 0 && V < TOPK) {
        int slot = V, t = 0, p = 0;
        while (slot < TOPK) {
            if (p < V && t == sselidx[p]) { t++; p++; }
            else {
                out_center[2 * slot] = t >> 10;
                out_center[2 * slot + 1] = t & (WW - 1);
                out_valid[slot] = 0;
                ctr2[slot] = make_float2(1e10f, 1e10f);
                t++; slot++;
            }
        }
    }
}

// ---------------- K4: nearest-center assignment + thing mask ----------------
// Centers staged in LDS (broadcast reads). Exact numpy-op-for-op f32 math
// (__f*_rn blocks fma contraction) so argmin ties resolve like the reference.
__global__ __launch_bounds__(256) void k4_assign(const int* __restrict__ sem,
                                                 const float* __restrict__ off,
                                                 const float2* __restrict__ ctr2,
                                                 int* __restrict__ out_inst) {
    __shared__ float2 c[TOPK];
    int tid = threadIdx.x;
    for (int t = tid; t < TOPK; t += 256) c[t] = ctr2[t];
    __syncthreads();
    int p = blockIdx.x * 256 + tid;
    int y = p >> 10, x = p & (WW - 1);
    float ly = __fadd_rn((float)y, off[p]);        // offsets[0,0]
    float lx = __fadd_rn((float)x, off[HW + p]);   // offsets[0,1]
    float best = INFINITY;
    int bid = 0;
    #pragma unroll 4
    for (int k = 0; k < TOPK; ++k) {
        float2 ck = c[k];
        float dy = __fsub_rn(ck.x, ly);
        float dx = __fsub_rn(ck.y, lx);
        float d2 = __fadd_rn(__fmul_rn(dy, dy), __fmul_rn(dx, dx));
        if (d2 < best) { best = d2; bid = k; }     // strict < = first-occurrence
    }
    int s = sem[p];
    unsigned t = (unsigned)(s - 11);               // THING_LIST = 11..18
    out_inst[p] = (t <= 7u) ? (bid + 1) : 0;
}

// ---------------- launch ----------------
extern "C" void kernel_launch(void* const* d_in, const int* in_sizes, int n_in,
                              void* d_out, int out_size, void* d_ws, size_t ws_size,
                              hipStream_t stream) {
    const int* sem = (const int*)d_in[0];
    const float* hmp = (const float*)d_in[1];
    const float* off = (const float*)d_in[2];
    int* out = (int*)d_out;

    // workspace layout (~459 KB; R1 used 592 KB ok)
    char* ws = (char*)d_ws;
    int* hist      = (int*)(ws);                          // 64 KB
    int* blkcnt    = (int*)(ws + 65536);                  // 8 KB
    float* blkscore = (float*)(ws + 73728);               // 192 KB
    int* blkidx    = (int*)(ws + 270336);                 // 192 KB
    float2* ctr2   = (float2*)(ws + 466944);              // 1.6 KB

    int* out_inst = out;                   // [1,H,W] int32
    int* out_center = out + HW;            // [1,K,2] int32 (y,x)
    int* out_valid = out + HW + 2 * TOPK;  // [K] 0/1

    hipMemsetAsync(hist, 0, NBINS * sizeof(int), stream);
    k1_nms<<<dim3(NBX, NBY), dim3(32, 8), 0, stream>>>(hmp, blkcnt, blkscore,
                                                       blkidx, hist);
    k3_select<<<1, 1024, 0, stream>>>(blkcnt, blkscore, blkidx, hist,
                                      out_center, out_valid, ctr2);
    k4_assign<<<HW / 256, 256, 0, stream>>>(sem, off, ctr2, out_inst);
}

// Round 3
// 119.116 us; speedup vs baseline: 1.5437x; 1.0248x over previous
//
#include <hip/hip_runtime.h>
#include <math.h>

// Problem constants (fixed by reference setup_inputs)
#define HH 512
#define WW 1024
#define HW (HH*WW)
#define TOPK 200
#define NMSPAD 3            // (7-1)/2
#define THRESH 0.1f
#define NBINS 8192          // LDS histogram bins (32 KB)
#define SUBCAP 1024         // suffix-subset capacity (expected m ~ 205)
#define SLOTS 24            // per-block candidate slots; 7x7-NMS max for 32x8 is 16
#define NBX 32              // grid x of k1 (WW/32)
#define NBY 64              // grid y of k1 (HH/8)
#define NB (NBX*NBY)        // 2048 blocks

// ---------------- helpers ----------------
__device__ __forceinline__ int score_bin(float s) {
    // monotone non-decreasing binning of scores in (0.1, 1]
    int b = (int)((s - THRESH) * (float)(NBINS / 0.9f));
    if (b < 0) b = 0;
    if (b > NBINS - 1) b = NBINS - 1;
    return b;
}

// ---------------- K1: threshold + 7x7 NMS -> per-block candidate lists ------
// Per-block LDS compaction; NO same-address global atomics (R1 post-mortem:
// one global counter serialized ~8192 wave-atomics -> 76 us). R3: histogram
// moved into k3's LDS, so k1 writes only its own slots -> zero contention.
__global__ __launch_bounds__(256) void k1_nms(const float* __restrict__ hmp,
                                              int* __restrict__ blkcnt,
                                              float* __restrict__ blkscore,
                                              int* __restrict__ blkidx) {
    const int BX = 32, BY = 8, TW = BX + 6, TH = BY + 6;
    __shared__ float A[TH][TW + 2];   // stride 40 breaks pow2 bank stride
    __shared__ float R[TH][BX];
    __shared__ float lsc[SLOTS];
    __shared__ int   lid[SLOTS];
    __shared__ int   s_cnt;
    int lx = threadIdx.x, ly = threadIdx.y;
    int x0 = blockIdx.x * BX, y0 = blockIdx.y * BY;
    int tid = ly * BX + lx;
    if (tid == 0) s_cnt = 0;

    for (int t = tid; t < TH * TW; t += 256) {
        int r = t / TW, c = t % TW;
        int gy = y0 - NMSPAD + r, gx = x0 - NMSPAD + c;
        float v = -INFINITY;  // reduce_window pads with init = -inf
        if (gy >= 0 && gy < HH && gx >= 0 && gx < WW) {
            float h = hmp[gy * WW + gx];
            v = (h > THRESH) ? h : -1.0f;
        }
        A[r][c] = v;
    }
    __syncthreads();
    for (int t = tid; t < TH * BX; t += 256) {
        int r = t / BX, c = t % BX;
        float m = A[r][c];
        #pragma unroll
        for (int d = 1; d < 7; ++d) m = fmaxf(m, A[r][c + d]);
        R[r][c] = m;
    }
    __syncthreads();
    float v = A[ly + NMSPAD][lx + NMSPAD];
    if (v > 0.0f) {                       // thresholded candidate
        float m = R[ly][lx];
        #pragma unroll
        for (int d = 1; d < 7; ++d) m = fmaxf(m, R[ly + d][lx]);
        if (v == m) {                     // local max (ties kept, like ref)
            int p = atomicAdd(&s_cnt, 1); // LDS atomic: ~1.3/block, cheap
            if (p < SLOTS) { lsc[p] = v; lid[p] = (y0 + ly) * WW + (x0 + lx); }
        }
    }
    __syncthreads();
    int b = blockIdx.y * NBX + blockIdx.x;
    int cnt = min(s_cnt, SLOTS);
    if (tid == 0) blkcnt[b] = cnt;
    if (tid < cnt) {
        blkscore[b * SLOTS + tid] = lsc[tid];
        blkidx[b * SLOTS + tid] = lid[tid];
    }
}

// ---------------- K3: exact top-K selection + ordering (single block) --------
// Builds the score histogram in LDS (no global hist, no memset dispatch).
// cutoff bin cb == bin of K-th largest score. Subset {bin >= cb} has size
// ~K + bin-mates; exact rank with top_k tie rule (higher score first,
// ties -> lower index). Output rows = valid centers sorted by flat idx
// (matches ref argsort(order_key)); V<K tail = lowest non-candidate indices.
__global__ __launch_bounds__(1024) void k3_select(const int* __restrict__ blkcnt,
                                                  const float* __restrict__ blkscore,
                                                  const int* __restrict__ blkidx,
                                                  int* __restrict__ out_center,
                                                  int* __restrict__ out_valid,
                                                  float2* __restrict__ ctr2) {
    __shared__ int hist[NBINS];      // 32 KB
    __shared__ int chunk[1024];      // 4 KB
    __shared__ float ss[SUBCAP];     // 4 KB
    __shared__ int sidx[SUBCAP];     // 4 KB
    __shared__ int srank[SUBCAP];    // 4 KB
    __shared__ int sselidx[TOPK];
    __shared__ int s_cb, s_m, s_V;
    int tid = threadIdx.x;

    // zero LDS hist + counters
    #pragma unroll
    for (int i = 0; i < NBINS / 1024; ++i) hist[tid + i * 1024] = 0;
    if (tid == 0) { s_m = 0; s_V = 0; }
    __syncthreads();

    // pass 1: LDS histogram + total count from per-block lists
    int myv = 0;
    for (int b = tid; b < NB; b += 1024) {
        int cnt = blkcnt[b];
        myv += cnt;
        for (int s = 0; s < cnt; ++s)
            atomicAdd(&hist[score_bin(blkscore[b * SLOTS + s])], 1);
    }
    if (myv) atomicAdd(&s_V, myv);
    __syncthreads();

    // per-thread 8-bin chunk sums
    int base = tid * (NBINS / 1024), sum = 0;
    #pragma unroll
    for (int i = 0; i < NBINS / 1024; ++i) sum += hist[base + i];
    chunk[tid] = sum;
    __syncthreads();

    if (tid == 0) {
        int acc = 0, cb = 0;
        for (int c = 1023; c >= 0; --c) {
            if (acc + chunk[c] >= TOPK) {
                for (int b = c * (NBINS / 1024) + (NBINS / 1024) - 1;
                     b >= c * (NBINS / 1024); --b) {
                    acc += hist[b];
                    if (acc >= TOPK) { cb = b; break; }
                }
                break;
            }
            acc += chunk[c];
        }
        s_cb = cb;   // stays 0 if total < K -> keep everything
    }
    __syncthreads();
    int cb = s_cb;
    int V = s_V;

    // pass 2: gather suffix subset from per-block lists into LDS
    for (int b = tid; b < NB; b += 1024) {
        int cnt = blkcnt[b];
        for (int s = 0; s < cnt; ++s) {
            float sc = blkscore[b * SLOTS + s];
            if (score_bin(sc) >= cb) {
                int p = atomicAdd(&s_m, 1);
                if (p < SUBCAP) { ss[p] = sc; sidx[p] = blkidx[b * SLOTS + s]; }
            }
        }
    }
    __syncthreads();
    int m = min(s_m, SUBCAP);

    // exact rank (top_k order) within subset
    for (int i = tid; i < m; i += 1024) {
        float si = ss[i]; int ii = sidx[i]; int r = 0;
        for (int j = 0; j < m; ++j) {
            float sj = ss[j];
            r += (sj > si) || (sj == si && sidx[j] < ii);
        }
        srank[i] = r;
    }
    __syncthreads();

    // selected (rank < K): output position = order by flat idx among selected
    for (int i = tid; i < m; i += 1024) {
        if (srank[i] < TOPK) {
            int ii = sidx[i];
            int pos = 0;
            for (int j = 0; j < m; ++j)
                pos += (srank[j] < TOPK) && (sidx[j] < ii);
            int y = ii >> 10, x = ii & (WW - 1);
            out_center[2 * pos] = y;
            out_center[2 * pos + 1] = x;
            out_valid[pos] = 1;
            ctr2[pos] = make_float2((float)y, (float)x);
            sselidx[pos] = ii;
        }
    }
    __syncthreads();

    // V < K tail: lowest non-candidate flat indices, invalid
    if (tid == 0 && V < TOPK) {
        int slot = V, t = 0, p = 0;
        while (slot < TOPK) {
            if (p < V && t == sselidx[p]) { t++; p++; }
            else {
                out_center[2 * slot] = t >> 10;
                out_center[2 * slot + 1] = t & (WW - 1);
                out_valid[slot] = 0;
                ctr2[slot] = make_float2(1e10f, 1e10f);
                t++; slot++;
            }
        }
    }
}

// ---------------- K4: nearest-center assignment + thing mask ----------------
// Centers staged in LDS (broadcast reads, conflict-free). Exact numpy-op-for-op
// f32 math (__f*_rn blocks fma contraction) so argmin ties resolve identically
// to the reference -- do NOT refactor to fma/expanded form (absmax ~199 risk).
__global__ __launch_bounds__(256) void k4_assign(const int* __restrict__ sem,
                                                 const float* __restrict__ off,
                                                 const float2* __restrict__ ctr2,
                                                 int* __restrict__ out_inst) {
    __shared__ float2 c[TOPK];
    int tid = threadIdx.x;
    for (int t = tid; t < TOPK; t += 256) c[t] = ctr2[t];
    __syncthreads();
    int p = blockIdx.x * 256 + tid;
    int y = p >> 10, x = p & (WW - 1);
    float ly = __fadd_rn((float)y, off[p]);        // offsets[0,0]
    float lx = __fadd_rn((float)x, off[HW + p]);   // offsets[0,1]
    float best = INFINITY;
    int bid = 0;
    #pragma unroll 4
    for (int k = 0; k < TOPK; ++k) {
        float2 ck = c[k];
        float dy = __fsub_rn(ck.x, ly);
        float dx = __fsub_rn(ck.y, lx);
        float d2 = __fadd_rn(__fmul_rn(dy, dy), __fmul_rn(dx, dx));
        if (d2 < best) { best = d2; bid = k; }     // strict < = first-occurrence
    }
    int s = sem[p];
    unsigned t = (unsigned)(s - 11);               // THING_LIST = 11..18
    out_inst[p] = (t <= 7u) ? (bid + 1) : 0;
}

// ---------------- launch ----------------
extern "C" void kernel_launch(void* const* d_in, const int* in_sizes, int n_in,
                              void* d_out, int out_size, void* d_ws, size_t ws_size,
                              hipStream_t stream) {
    const int* sem = (const int*)d_in[0];
    const float* hmp = (const float*)d_in[1];
    const float* off = (const float*)d_in[2];
    int* out = (int*)d_out;

    // workspace layout (~394 KB)
    char* ws = (char*)d_ws;
    int* blkcnt     = (int*)(ws);                         // 8 KB
    float* blkscore = (float*)(ws + 8192);                // 192 KB
    int* blkidx     = (int*)(ws + 204800);                // 192 KB
    float2* ctr2    = (float2*)(ws + 401408);             // 1.6 KB

    int* out_inst = out;                   // [1,H,W] int32
    int* out_center = out + HW;            // [1,K,2] int32 (y,x)
    int* out_valid = out + HW + 2 * TOPK;  // [K] 0/1

    k1_nms<<<dim3(NBX, NBY), dim3(32, 8), 0, stream>>>(hmp, blkcnt, blkscore,
                                                       blkidx);
    k3_select<<<1, 1024, 0, stream>>>(blkcnt, blkscore, blkidx,
                                      out_center, out_valid, ctr2);
    k4_assign<<<HW / 256, 256, 0, stream>>>(sem, off, ctr2, out_inst);
}

// Round 4
// 103.803 us; speedup vs baseline: 1.7715x; 1.1475x over previous
//
#include <hip/hip_runtime.h>
#include <math.h>

// Problem constants (fixed by reference setup_inputs)
#define HH 512
#define WW 1024
#define HW (HH*WW)
#define TOPK 200
#define NMSPAD 3            // (7-1)/2
#define THRESH 0.1f
#define NBINS 8192          // LDS histogram bins (32 KB)
#define SUBCAP 1024         // suffix-subset capacity (expected m ~ 205)
#define SLOTS 24            // per-block candidate slots; 7x7-NMS max for 32x8 is 16
#define NBX 32              // grid x of k1 (WW/32)
#define NBY 64              // grid y of k1 (HH/8)
#define NB (NBX*NBY)        // 2048 blocks

// ---------------- helpers ----------------
__device__ __forceinline__ int score_bin(float s) {
    // monotone non-decreasing binning of scores in (0.1, 1]
    int b = (int)((s - THRESH) * (float)(NBINS / 0.9f));
    if (b < 0) b = 0;
    if (b > NBINS - 1) b = NBINS - 1;
    return b;
}

// ---------------- K1: threshold + 7x7 NMS -> per-block candidate lists ------
// Per-block LDS compaction; NO same-address global atomics (R1 post-mortem:
// one global counter serialized ~8192 wave-atomics -> 76 us).
__global__ __launch_bounds__(256) void k1_nms(const float* __restrict__ hmp,
                                              int* __restrict__ blkcnt,
                                              float* __restrict__ blkscore,
                                              int* __restrict__ blkidx) {
    const int BX = 32, BY = 8, TW = BX + 6, TH = BY + 6;
    __shared__ float A[TH][TW + 2];   // stride 40 breaks pow2 bank stride
    __shared__ float R[TH][BX];
    __shared__ float lsc[SLOTS];
    __shared__ int   lid[SLOTS];
    __shared__ int   s_cnt;
    int lx = threadIdx.x, ly = threadIdx.y;
    int x0 = blockIdx.x * BX, y0 = blockIdx.y * BY;
    int tid = ly * BX + lx;
    if (tid == 0) s_cnt = 0;

    for (int t = tid; t < TH * TW; t += 256) {
        int r = t / TW, c = t % TW;
        int gy = y0 - NMSPAD + r, gx = x0 - NMSPAD + c;
        float v = -INFINITY;  // reduce_window pads with init = -inf
        if (gy >= 0 && gy < HH && gx >= 0 && gx < WW) {
            float h = hmp[gy * WW + gx];
            v = (h > THRESH) ? h : -1.0f;
        }
        A[r][c] = v;
    }
    __syncthreads();
    for (int t = tid; t < TH * BX; t += 256) {
        int r = t / BX, c = t % BX;
        float m = A[r][c];
        #pragma unroll
        for (int d = 1; d < 7; ++d) m = fmaxf(m, A[r][c + d]);
        R[r][c] = m;
    }
    __syncthreads();
    float v = A[ly + NMSPAD][lx + NMSPAD];
    if (v > 0.0f) {                       // thresholded candidate
        float m = R[ly][lx];
        #pragma unroll
        for (int d = 1; d < 7; ++d) m = fmaxf(m, R[ly + d][lx]);
        if (v == m) {                     // local max (ties kept, like ref)
            int p = atomicAdd(&s_cnt, 1); // LDS atomic: ~1.3/block, cheap
            if (p < SLOTS) { lsc[p] = v; lid[p] = (y0 + ly) * WW + (x0 + lx); }
        }
    }
    __syncthreads();
    int b = blockIdx.y * NBX + blockIdx.x;
    int cnt = min(s_cnt, SLOTS);
    if (tid == 0) blkcnt[b] = cnt;
    if (tid < cnt) {
        blkscore[b * SLOTS + tid] = lsc[tid];
        blkidx[b * SLOTS + tid] = lid[tid];
    }
}

// ---------------- K3: exact top-K selection + ordering (single block) --------
// LDS histogram -> cutoff bin of K-th largest score -> exact rank within the
// suffix subset (top_k tie rule: higher score first, ties -> lower index).
// Output rows = valid centers sorted by flat idx (matches argsort(order_key));
// V<K tail = lowest non-candidate indices. Centers therefore ASCEND in y,
// which k4's range pruning relies on.
__global__ __launch_bounds__(1024) void k3_select(const int* __restrict__ blkcnt,
                                                  const float* __restrict__ blkscore,
                                                  const int* __restrict__ blkidx,
                                                  int* __restrict__ out_center,
                                                  int* __restrict__ out_valid,
                                                  float2* __restrict__ ctr2) {
    __shared__ int hist[NBINS];      // 32 KB
    __shared__ int chunk[1024];      // 4 KB
    __shared__ float ss[SUBCAP];     // 4 KB
    __shared__ int sidx[SUBCAP];     // 4 KB
    __shared__ int srank[SUBCAP];    // 4 KB
    __shared__ int sselidx[TOPK];
    __shared__ int s_cb, s_m, s_V;
    int tid = threadIdx.x;

    #pragma unroll
    for (int i = 0; i < NBINS / 1024; ++i) hist[tid + i * 1024] = 0;
    if (tid == 0) { s_m = 0; s_V = 0; }
    __syncthreads();

    // pass 1: LDS histogram + total count from per-block lists
    int myv = 0;
    for (int b = tid; b < NB; b += 1024) {
        int cnt = blkcnt[b];
        myv += cnt;
        for (int s = 0; s < cnt; ++s)
            atomicAdd(&hist[score_bin(blkscore[b * SLOTS + s])], 1);
    }
    if (myv) atomicAdd(&s_V, myv);
    __syncthreads();

    int base = tid * (NBINS / 1024), sum = 0;
    #pragma unroll
    for (int i = 0; i < NBINS / 1024; ++i) sum += hist[base + i];
    chunk[tid] = sum;
    __syncthreads();

    if (tid == 0) {
        int acc = 0, cb = 0;
        for (int c = 1023; c >= 0; --c) {
            if (acc + chunk[c] >= TOPK) {
                for (int b = c * (NBINS / 1024) + (NBINS / 1024) - 1;
                     b >= c * (NBINS / 1024); --b) {
                    acc += hist[b];
                    if (acc >= TOPK) { cb = b; break; }
                }
                break;
            }
            acc += chunk[c];
        }
        s_cb = cb;   // stays 0 if total < K -> keep everything
    }
    __syncthreads();
    int cb = s_cb;
    int V = s_V;

    // pass 2: gather suffix subset into LDS
    for (int b = tid; b < NB; b += 1024) {
        int cnt = blkcnt[b];
        for (int s = 0; s < cnt; ++s) {
            float sc = blkscore[b * SLOTS + s];
            if (score_bin(sc) >= cb) {
                int p = atomicAdd(&s_m, 1);
                if (p < SUBCAP) { ss[p] = sc; sidx[p] = blkidx[b * SLOTS + s]; }
            }
        }
    }
    __syncthreads();
    int m = min(s_m, SUBCAP);

    // exact rank (top_k order) within subset
    for (int i = tid; i < m; i += 1024) {
        float si = ss[i]; int ii = sidx[i]; int r = 0;
        for (int j = 0; j < m; ++j) {
            float sj = ss[j];
            r += (sj > si) || (sj == si && sidx[j] < ii);
        }
        srank[i] = r;
    }
    __syncthreads();

    // selected (rank < K): output position = order by flat idx among selected
    for (int i = tid; i < m; i += 1024) {
        if (srank[i] < TOPK) {
            int ii = sidx[i];
            int pos = 0;
            for (int j = 0; j < m; ++j)
                pos += (srank[j] < TOPK) && (sidx[j] < ii);
            int y = ii >> 10, x = ii & (WW - 1);
            out_center[2 * pos] = y;
            out_center[2 * pos + 1] = x;
            out_valid[pos] = 1;
            ctr2[pos] = make_float2((float)y, (float)x);
            sselidx[pos] = ii;
        }
    }
    __syncthreads();

    // V < K tail: lowest non-candidate flat indices, invalid
    if (tid == 0 && V < TOPK) {
        int slot = V, t = 0, p = 0;
        while (slot < TOPK) {
            if (p < V && t == sselidx[p]) { t++; p++; }
            else {
                out_center[2 * slot] = t >> 10;
                out_center[2 * slot + 1] = t & (WW - 1);
                out_valid[slot] = 0;
                ctr2[slot] = make_float2(1e10f, 1e10f);
                t++; slot++;
            }
        }
    }
}

// ---------------- K4: nearest-center assignment + thing mask ----------------
// Exact-safe range pruning. Each wave covers 64 pixels of ONE row. We compute
// the wave's bbox of predicted locations (exact f32 values), then for every
// center a rounding-conservative lower bound lb_k (<= d2(p,k) for all p in
// wave, by monotonicity of round-to-nearest) and an upper bound ub (>= best
// final distance of every p). Centers with lb_k > ub are STRICTLY worse than
// the final best for every pixel -> skipping them cannot change argmin or tie
// order. Centers ascend in y (k3 sorts by flat idx), so the kept set lies in a
// contiguous k-range. Main loop over that range is op-for-op identical to the
// reference (__f*_rn, no contraction) -> bit-exact argmin.
__global__ __launch_bounds__(256) void k4_assign(const int* __restrict__ sem,
                                                 const float* __restrict__ off,
                                                 const float2* __restrict__ ctr2,
                                                 int* __restrict__ out_inst) {
    __shared__ float2 c[TOPK];
    int tid = threadIdx.x;
    if (tid < TOPK) c[tid] = ctr2[tid];
    __syncthreads();

    int p = blockIdx.x * 256 + tid;
    int y = p >> 10, x = p & (WW - 1);
    float ly = __fadd_rn((float)y, off[p]);        // offsets[0,0]
    float lx = __fadd_rn((float)x, off[HW + p]);   // offsets[0,1]

    // wave bbox of (ly,lx) — min/max are exact, no rounding introduced
    float ymin = ly, ymax = ly, xmin = lx, xmax = lx;
    #pragma unroll
    for (int mdist = 32; mdist >= 1; mdist >>= 1) {
        ymin = fminf(ymin, __shfl_xor(ymin, mdist, 64));
        ymax = fmaxf(ymax, __shfl_xor(ymax, mdist, 64));
        xmin = fminf(xmin, __shfl_xor(xmin, mdist, 64));
        xmax = fmaxf(xmax, __shfl_xor(xmax, mdist, 64));
    }

    int lane = tid & 63;
    float ub = INFINITY;
    float lbv[4];
    // lanes cover centers k = r*64 + lane
    #pragma unroll
    for (int r = 0; r < 4; ++r) {
        int k = r * 64 + lane;
        float lb = INFINITY;
        float u = INFINITY;
        if (k < TOPK) {
            float2 ck = c[k];
            // far-corner bound: dyM >= |rn(cy - ly)| for all ly in [ymin,ymax]
            float dyM = fmaxf(__fsub_rn(ck.x, ymin), __fsub_rn(ymax, ck.x));
            float dxM = fmaxf(__fsub_rn(ck.y, xmin), __fsub_rn(xmax, ck.y));
            u = __fadd_rn(__fmul_rn(dyM, dyM), __fmul_rn(dxM, dxM));
            // near-corner bound: dyL <= |rn(cy - ly)| for all ly in [ymin,ymax]
            float dyL = fmaxf(0.0f, fmaxf(__fsub_rn(ck.x, ymax), __fsub_rn(ymin, ck.x)));
            float dxL = fmaxf(0.0f, fmaxf(__fsub_rn(ck.y, xmax), __fsub_rn(xmin, ck.y)));
            lb = __fadd_rn(__fmul_rn(dyL, dyL), __fmul_rn(dxL, dxL));
        }
        ub = fminf(ub, u);
        lbv[r] = lb;
    }
    #pragma unroll
    for (int mdist = 32; mdist >= 1; mdist >>= 1)
        ub = fminf(ub, __shfl_xor(ub, mdist, 64));

    // contiguous kept range [ka, kb) — superset of {k : lb_k <= ub}
    int ka = TOPK, kb = 0;
    #pragma unroll
    for (int r = 0; r < 4; ++r) {
        unsigned long long m = __ballot(lbv[r] <= ub);
        if (m) {
            int lo = r * 64 + __builtin_ctzll(m);
            int hi = r * 64 + 63 - __builtin_clzll(m);
            ka = min(ka, lo);
            kb = max(kb, hi + 1);
        }
    }
    if (ka >= kb) { ka = 0; kb = TOPK; }   // safety net; provably unreachable

    // main loop: op-for-op identical to reference over the kept range
    float best = INFINITY;
    int bid = 0;
    #pragma unroll 4
    for (int k = ka; k < kb; ++k) {
        float2 ck = c[k];
        float dy = __fsub_rn(ck.x, ly);
        float dx = __fsub_rn(ck.y, lx);
        float d2 = __fadd_rn(__fmul_rn(dy, dy), __fmul_rn(dx, dx));
        if (d2 < best) { best = d2; bid = k; }   // strict < = first-occurrence
    }
    int s = sem[p];
    unsigned t = (unsigned)(s - 11);             // THING_LIST = 11..18
    out_inst[p] = (t <= 7u) ? (bid + 1) : 0;
}

// ---------------- launch ----------------
extern "C" void kernel_launch(void* const* d_in, const int* in_sizes, int n_in,
                              void* d_out, int out_size, void* d_ws, size_t ws_size,
                              hipStream_t stream) {
    const int* sem = (const int*)d_in[0];
    const float* hmp = (const float*)d_in[1];
    const float* off = (const float*)d_in[2];
    int* out = (int*)d_out;

    // workspace layout (~394 KB)
    char* ws = (char*)d_ws;
    int* blkcnt     = (int*)(ws);                         // 8 KB
    float* blkscore = (float*)(ws + 8192);                // 192 KB
    int* blkidx     = (int*)(ws + 204800);                // 192 KB
    float2* ctr2    = (float2*)(ws + 401408);             // 1.6 KB

    int* out_inst = out;                   // [1,H,W] int32
    int* out_center = out + HW;            // [1,K,2] int32 (y,x)
    int* out_valid = out + HW + 2 * TOPK;  // [K] 0/1

    k1_nms<<<dim3(NBX, NBY), dim3(32, 8), 0, stream>>>(hmp, blkcnt, blkscore,
                                                       blkidx);
    k3_select<<<1, 1024, 0, stream>>>(blkcnt, blkscore, blkidx,
                                      out_center, out_valid, ctr2);
    k4_assign<<<HW / 256, 256, 0, stream>>>(sem, off, ctr2, out_inst);
}

// Round 5
// 101.593 us; speedup vs baseline: 1.8100x; 1.0218x over previous
//
#include <hip/hip_runtime.h>
#include <math.h>

// Problem constants (fixed by reference setup_inputs)
#define HH 512
#define WW 1024
#define HW (HH*WW)
#define TOPK 200
#define NMSPAD 3            // (7-1)/2
#define THRESH 0.1f
#define NBINS 4096          // LDS histogram bins (16 KB); binning exact for any count
#define SUBCAP 1024         // suffix-subset capacity (expected m ~ 205)
#define SLOTS 24            // per-block candidate slots; 7x7-NMS max for 32x8 is 16
#define NBX 32              // grid x of k1 (WW/32)
#define NBY 64              // grid y of k1 (HH/8)
#define NB (NBX*NBY)        // 2048 blocks

// ---------------- helpers ----------------
__device__ __forceinline__ int score_bin(float s) {
    // monotone non-decreasing binning of scores in (0.1, 1]
    int b = (int)((s - THRESH) * (float)(NBINS / 0.9f));
    if (b < 0) b = 0;
    if (b > NBINS - 1) b = NBINS - 1;
    return b;
}

// ---------------- K1: threshold + 7x7 NMS -> per-block candidate lists ------
// Per-block LDS compaction; NO same-address global atomics (R1 post-mortem:
// one global counter serialized ~8192 wave-atomics -> 76 us).
__global__ __launch_bounds__(256) void k1_nms(const float* __restrict__ hmp,
                                              int* __restrict__ blkcnt,
                                              float* __restrict__ blkscore,
                                              int* __restrict__ blkidx) {
    const int BX = 32, BY = 8, TW = BX + 6, TH = BY + 6;
    __shared__ float A[TH][TW + 2];   // stride 40 breaks pow2 bank stride
    __shared__ float R[TH][BX];
    __shared__ float lsc[SLOTS];
    __shared__ int   lid[SLOTS];
    __shared__ int   s_cnt;
    int lx = threadIdx.x, ly = threadIdx.y;
    int x0 = blockIdx.x * BX, y0 = blockIdx.y * BY;
    int tid = ly * BX + lx;
    if (tid == 0) s_cnt = 0;

    for (int t = tid; t < TH * TW; t += 256) {
        int r = t / TW, c = t % TW;
        int gy = y0 - NMSPAD + r, gx = x0 - NMSPAD + c;
        float v = -INFINITY;  // reduce_window pads with init = -inf
        if (gy >= 0 && gy < HH && gx >= 0 && gx < WW) {
            float h = hmp[gy * WW + gx];
            v = (h > THRESH) ? h : -1.0f;
        }
        A[r][c] = v;
    }
    __syncthreads();
    for (int t = tid; t < TH * BX; t += 256) {
        int r = t / BX, c = t % BX;
        float m = A[r][c];
        #pragma unroll
        for (int d = 1; d < 7; ++d) m = fmaxf(m, A[r][c + d]);
        R[r][c] = m;
    }
    __syncthreads();
    float v = A[ly + NMSPAD][lx + NMSPAD];
    if (v > 0.0f) {                       // thresholded candidate
        float m = R[ly][lx];
        #pragma unroll
        for (int d = 1; d < 7; ++d) m = fmaxf(m, R[ly + d][lx]);
        if (v == m) {                     // local max (ties kept, like ref)
            int p = atomicAdd(&s_cnt, 1); // LDS atomic: ~1.3/block, cheap
            if (p < SLOTS) { lsc[p] = v; lid[p] = (y0 + ly) * WW + (x0 + lx); }
        }
    }
    __syncthreads();
    int b = blockIdx.y * NBX + blockIdx.x;
    int cnt = min(s_cnt, SLOTS);
    if (tid == 0) blkcnt[b] = cnt;
    if (tid < cnt) {
        blkscore[b * SLOTS + tid] = lsc[tid];
        blkidx[b * SLOTS + tid] = lid[tid];
    }
}

// ---------------- K3: exact top-K selection + ordering (single block) --------
// LDS histogram -> cutoff bin of K-th largest score -> exact rank within the
// suffix subset (top_k tie rule: higher score first, ties -> lower index).
// Output rows = valid centers sorted by flat idx (matches argsort(order_key));
// V<K tail = lowest non-candidate indices. Exact under ANY binning: cb is the
// bin of the K-th largest, subset {bin >= cb} provably contains the top-K.
__global__ __launch_bounds__(1024) void k3_select(const int* __restrict__ blkcnt,
                                                  const float* __restrict__ blkscore,
                                                  const int* __restrict__ blkidx,
                                                  int* __restrict__ out_center,
                                                  int* __restrict__ out_valid,
                                                  float2* __restrict__ ctr2) {
    __shared__ int hist[NBINS];      // 16 KB
    __shared__ int chunk[1024];      // 4 KB
    __shared__ float ss[SUBCAP];     // 4 KB
    __shared__ int sidx[SUBCAP];     // 4 KB
    __shared__ int srank[SUBCAP];    // 4 KB
    __shared__ int sselidx[TOPK];
    __shared__ int s_cb, s_m, s_V;
    int tid = threadIdx.x;

    #pragma unroll
    for (int i = 0; i < NBINS / 1024; ++i) hist[tid + i * 1024] = 0;
    if (tid == 0) { s_m = 0; s_V = 0; }
    __syncthreads();

    // pass 1: LDS histogram + total count from per-block lists
    int myv = 0;
    for (int b = tid; b < NB; b += 1024) {
        int cnt = blkcnt[b];
        myv += cnt;
        for (int s = 0; s < cnt; ++s)
            atomicAdd(&hist[score_bin(blkscore[b * SLOTS + s])], 1);
    }
    if (myv) atomicAdd(&s_V, myv);
    __syncthreads();

    int base = tid * (NBINS / 1024), sum = 0;
    #pragma unroll
    for (int i = 0; i < NBINS / 1024; ++i) sum += hist[base + i];
    chunk[tid] = sum;
    __syncthreads();

    if (tid == 0) {
        int acc = 0, cb = 0;
        for (int c = 1023; c >= 0; --c) {
            if (acc + chunk[c] >= TOPK) {
                for (int b = c * (NBINS / 1024) + (NBINS / 1024) - 1;
                     b >= c * (NBINS / 1024); --b) {
                    acc += hist[b];
                    if (acc >= TOPK) { cb = b; break; }
                }
                break;
            }
            acc += chunk[c];
        }
        s_cb = cb;   // stays 0 if total < K -> keep everything
    }
    __syncthreads();
    int cb = s_cb;
    int V = s_V;

    // pass 2: gather suffix subset into LDS (blk lists are L2-hot from k1)
    for (int b = tid; b < NB; b += 1024) {
        int cnt = blkcnt[b];
        for (int s = 0; s < cnt; ++s) {
            float sc = blkscore[b * SLOTS + s];
            if (score_bin(sc) >= cb) {
                int p = atomicAdd(&s_m, 1);
                if (p < SUBCAP) { ss[p] = sc; sidx[p] = blkidx[b * SLOTS + s]; }
            }
        }
    }
    __syncthreads();
    int m = min(s_m, SUBCAP);

    // exact rank (top_k order) within subset
    for (int i = tid; i < m; i += 1024) {
        float si = ss[i]; int ii = sidx[i]; int r = 0;
        for (int j = 0; j < m; ++j) {
            float sj = ss[j];
            r += (sj > si) || (sj == si && sidx[j] < ii);
        }
        srank[i] = r;
    }
    __syncthreads();

    // selected (rank < K): output position = order by flat idx among selected
    for (int i = tid; i < m; i += 1024) {
        if (srank[i] < TOPK) {
            int ii = sidx[i];
            int pos = 0;
            for (int j = 0; j < m; ++j)
                pos += (srank[j] < TOPK) && (sidx[j] < ii);
            int y = ii >> 10, x = ii & (WW - 1);
            out_center[2 * pos] = y;
            out_center[2 * pos + 1] = x;
            out_valid[pos] = 1;
            ctr2[pos] = make_float2((float)y, (float)x);
            sselidx[pos] = ii;
        }
    }
    __syncthreads();

    // V < K tail: lowest non-candidate flat indices, invalid
    if (tid == 0 && V < TOPK) {
        int slot = V, t = 0, p = 0;
        while (slot < TOPK) {
            if (p < V && t == sselidx[p]) { t++; p++; }
            else {
                out_center[2 * slot] = t >> 10;
                out_center[2 * slot + 1] = t & (WW - 1);
                out_valid[slot] = 0;
                ctr2[slot] = make_float2(1e10f, 1e10f);
                t++; slot++;
            }
        }
    }
}

// ---------------- K4: nearest-center assignment + thing mask ----------------
// Exact-safe pruning, R5: iterate the wave-uniform keep-MASK bits instead of
// the contiguous [ka,kb) superset (~40 vs ~70 centers). Proof sketch: for a
// skipped center k, lb_k > ub >= best_final(p) for every pixel p in the wave,
// and lb_k <= d2(p,k) by monotonicity of round-to-nearest, so d2(p,k) > best
// STRICTLY -> cannot win nor tie. Kept centers are visited in ascending k
// (r-chunks ascending, ctz ascending), and the body is op-for-op identical to
// the reference (__f*_rn, no fma contraction) -> bit-exact argmin + tie order.
__global__ __launch_bounds__(256) void k4_assign(const int* __restrict__ sem,
                                                 const float* __restrict__ off,
                                                 const float2* __restrict__ ctr2,
                                                 int* __restrict__ out_inst) {
    __shared__ float2 c[TOPK];
    int tid = threadIdx.x;
    if (tid < TOPK) c[tid] = ctr2[tid];
    __syncthreads();

    int p = blockIdx.x * 256 + tid;
    int y = p >> 10, x = p & (WW - 1);
    int s = sem[p];                                // hoist: overlap latency
    float ly = __fadd_rn((float)y, off[p]);        // offsets[0,0]
    float lx = __fadd_rn((float)x, off[HW + p]);   // offsets[0,1]

    // wave bbox of (ly,lx) — min/max are exact, no rounding introduced
    float ymin = ly, ymax = ly, xmin = lx, xmax = lx;
    #pragma unroll
    for (int mdist = 32; mdist >= 1; mdist >>= 1) {
        ymin = fminf(ymin, __shfl_xor(ymin, mdist, 64));
        ymax = fmaxf(ymax, __shfl_xor(ymax, mdist, 64));
        xmin = fminf(xmin, __shfl_xor(xmin, mdist, 64));
        xmax = fmaxf(xmax, __shfl_xor(xmax, mdist, 64));
    }

    int lane = tid & 63;
    float ub = INFINITY;
    float lbv[4];
    // lane covers centers k = r*64 + lane
    #pragma unroll
    for (int r = 0; r < 4; ++r) {
        int k = r * 64 + lane;
        float lb = INFINITY;
        float u = INFINITY;
        if (k < TOPK) {
            float2 ck = c[k];
            // far-corner bound: dyM >= |rn(cy - ly)| for all ly in [ymin,ymax]
            float dyM = fmaxf(__fsub_rn(ck.x, ymin), __fsub_rn(ymax, ck.x));
            float dxM = fmaxf(__fsub_rn(ck.y, xmin), __fsub_rn(xmax, ck.y));
            u = __fadd_rn(__fmul_rn(dyM, dyM), __fmul_rn(dxM, dxM));
            // near-corner bound: dyL <= |rn(cy - ly)| for all ly in [ymin,ymax]
            float dyL = fmaxf(0.0f, fmaxf(__fsub_rn(ck.x, ymax), __fsub_rn(ymin, ck.x)));
            float dxL = fmaxf(0.0f, fmaxf(__fsub_rn(ck.y, xmax), __fsub_rn(xmin, ck.y)));
            lb = __fadd_rn(__fmul_rn(dyL, dyL), __fmul_rn(dxL, dxL));
        }
        ub = fminf(ub, u);
        lbv[r] = lb;
    }
    #pragma unroll
    for (int mdist = 32; mdist >= 1; mdist >>= 1)
        ub = fminf(ub, __shfl_xor(ub, mdist, 64));

    // wave-uniform keep masks (bit lane of km[r] = keep center r*64+lane)
    unsigned long long km[4];
    #pragma unroll
    for (int r = 0; r < 4; ++r) km[r] = __ballot(lbv[r] <= ub);
    if (!(km[0] | km[1] | km[2] | km[3])) {        // safety net; unreachable
        km[0] = km[1] = km[2] = ~0ull; km[3] = 0xFFull;
    }

    float best = INFINITY;
    int bid = 0;
    #pragma unroll
    for (int r = 0; r < 4; ++r) {
        unsigned long long msk = km[r];
        while (msk) {                              // uniform flow, ascending k
            int k = r * 64 + __builtin_ctzll(msk);
            msk &= msk - 1;
            float2 ck = c[k];                      // uniform k -> LDS broadcast
            float dy = __fsub_rn(ck.x, ly);
            float dx = __fsub_rn(ck.y, lx);
            float d2 = __fadd_rn(__fmul_rn(dy, dy), __fmul_rn(dx, dx));
            if (d2 < best) { best = d2; bid = k; } // strict < = first-occurrence
        }
    }
    unsigned t = (unsigned)(s - 11);               // THING_LIST = 11..18
    out_inst[p] = (t <= 7u) ? (bid + 1) : 0;
}

// ---------------- launch ----------------
extern "C" void kernel_launch(void* const* d_in, const int* in_sizes, int n_in,
                              void* d_out, int out_size, void* d_ws, size_t ws_size,
                              hipStream_t stream) {
    const int* sem = (const int*)d_in[0];
    const float* hmp = (const float*)d_in[1];
    const float* off = (const float*)d_in[2];
    int* out = (int*)d_out;

    // workspace layout (~394 KB)
    char* ws = (char*)d_ws;
    int* blkcnt     = (int*)(ws);                         // 8 KB
    float* blkscore = (float*)(ws + 8192);                // 192 KB
    int* blkidx     = (int*)(ws + 204800);                // 192 KB
    float2* ctr2    = (float2*)(ws + 401408);             // 1.6 KB

    int* out_inst = out;                   // [1,H,W] int32
    int* out_center = out + HW;            // [1,K,2] int32 (y,x)
    int* out_valid = out + HW + 2 * TOPK;  // [K] 0/1

    k1_nms<<<dim3(NBX, NBY), dim3(32, 8), 0, stream>>>(hmp, blkcnt, blkscore,
                                                       blkidx);
    k3_select<<<1, 1024, 0, stream>>>(blkcnt, blkscore, blkidx,
                                      out_center, out_valid, ctr2);
    k4_assign<<<HW / 256, 256, 0, stream>>>(sem, off, ctr2, out_inst);
}